// Round 9
// baseline (307.572 us; speedup 1.0000x reference)
//
#include <hip/hip_runtime.h>
#include <hip/hip_fp16.h>

static constexpr float FILLW = 2.0f;
static constexpr int BSH  = 6;      // 64 nodes per coarse bucket
static constexpr int CAPB = 1792;   // bucket capacity (mean 1024, sd ~32 -> 24 sigma)
static constexpr int NPB  = 256;    // partition blocks per tower
static constexpr int EPT  = 8;      // partition edges/thread batch (ILP)

// packed f16 helpers (VOP3P); keep values as 32-bit words
__device__ __forceinline__ unsigned pk_mul(unsigned a, unsigned b){
    unsigned r; asm("v_pk_mul_f16 %0, %1, %2" : "=v"(r) : "v"(a), "v"(b)); return r;
}
__device__ __forceinline__ unsigned pk_max(unsigned a, unsigned b){
    unsigned r; asm("v_pk_max_f16 %0, %1, %2" : "=v"(r) : "v"(a), "v"(b)); return r;
}

// ======================= register-blocked GEMM tile =======================
// W is NOT staged in LDS: it is 32KB (fits L1), read uniformly by all waves ->
// L1-broadcast hits. Dropping Ws cuts static LDS 48->16KB (gemm2: 40->8KB),
// lifting blocks/CU from 3 to 4+ (occupancy was the measured binding limit).
template<int F, int K, int TR, int KC, bool SCALE, typename OutT>
__device__ __forceinline__ void gemm_tile(const float* __restrict__ A,
        const float* __restrict__ W, OutT* __restrict__ C,
        const float* __restrict__ dv, int rb, int N,
        float* __restrict__ As){
    constexpr int NCH = K / KC;
    constexpr int TRp = TR;           // PAD=0 verified conflict-free
    constexpr int CG  = F / 8;
    constexpr int LPT = TR * KC / 1024;
    const int tid = threadIdx.x;
    const int tx = tid % CG, ty = tid / CG;
    const int c0 = tx * 8, r0 = ty * 8;

    float acc[8][8];
    #pragma unroll
    for (int i = 0; i < 8; ++i)
        #pragma unroll
        for (int j = 0; j < 8; ++j) acc[i][j] = 0.f;

    float4 st[LPT];
    auto gload = [&](int kc){
        #pragma unroll
        for (int l2 = 0; l2 < LPT; ++l2){
            int l = l2 * 256 + tid;
            int r = l / (KC / 4);
            int kk = (l % (KC / 4)) * 4;
            int ar = rb + r; if (ar >= N) ar = N - 1;
            st[l2] = *(const float4*)(A + (size_t)ar * K + kc * KC + kk);
        }
    };
    auto swrite = [&](int buf){
        float* p = As + buf * (KC * TRp);
        #pragma unroll
        for (int l2 = 0; l2 < LPT; ++l2){
            int l = l2 * 256 + tid;
            int r = l / (KC / 4);
            int kk = (l % (KC / 4)) * 4;
            p[(kk+0)*TRp + r] = st[l2].x;
            p[(kk+1)*TRp + r] = st[l2].y;
            p[(kk+2)*TRp + r] = st[l2].z;
            p[(kk+3)*TRp + r] = st[l2].w;
        }
    };

    gload(0); swrite(0);
    __syncthreads();
    for (int kc = 0; kc < NCH; ++kc){
        if (kc + 1 < NCH) gload(kc + 1);
        const float* Ab = As + (kc & 1) * (KC * TRp);
        #pragma unroll
        for (int j = 0; j < KC; ++j){
            const float* wrow = W + (size_t)(kc * KC + j) * F + c0;
            float4 w0 = *(const float4*)(wrow);
            float4 w1 = *(const float4*)(wrow + 4);
            float4 a0 = *(const float4*)(Ab + j * TRp + r0);
            float4 a1 = *(const float4*)(Ab + j * TRp + r0 + 4);
            float av[8] = {a0.x,a0.y,a0.z,a0.w,a1.x,a1.y,a1.z,a1.w};
            float wvv[8] = {w0.x,w0.y,w0.z,w0.w,w1.x,w1.y,w1.z,w1.w};
            #pragma unroll
            for (int rr = 0; rr < 8; ++rr)
                #pragma unroll
                for (int cc = 0; cc < 8; ++cc)
                    acc[rr][cc] = fmaf(av[rr], wvv[cc], acc[rr][cc]);
        }
        if (kc + 1 < NCH){ swrite((kc + 1) & 1); __syncthreads(); }
    }
    #pragma unroll
    for (int rr = 0; rr < 8; ++rr){
        int row = rb + r0 + rr;
        if (row < N){
            float scv = 1.0f;
            if constexpr (SCALE) scv = dv[row];
            if constexpr (sizeof(OutT) == 2){
                __half2 o2[4];
                #pragma unroll
                for (int q = 0; q < 4; ++q)
                    o2[q] = __floats2half2_rn(acc[rr][2*q]*scv, acc[rr][2*q+1]*scv);
                *(float4*)((__half*)C + (size_t)row * F + c0) = *(float4*)o2;
            } else {
                float4 o0 = {acc[rr][0]*scv, acc[rr][1]*scv, acc[rr][2]*scv, acc[rr][3]*scv};
                float4 o1 = {acc[rr][4]*scv, acc[rr][5]*scv, acc[rr][6]*scv, acc[rr][7]*scv};
                *(float4*)((float*)C + (size_t)row * F + c0)     = o0;
                *(float4*)((float*)C + (size_t)row * F + c0 + 4) = o1;
            }
        }
    }
}

// XCD-pinned decomposition: blockIdx%8 ~= XCD; XCDs 0-3 -> tower 0, 4-7 -> tower 1.
__device__ __forceinline__ void xcd_map(int c, int TW2, int LIN_BPT,
                                        int& t, int& chunk){
    if (TW2){ int x = c & 7; t = x >> 2; chunk = (c >> 3) * 4 + (x & 3); }
    else    { t = c / LIN_BPT; chunk = c - t * LIN_BPT; }
}

// ===== fused: GEMM1 (fp16 out, both towers) + coarse-bucket edge partition =====
// Static LDS = 16KB (As only); hist aliases As. Partition: LDS histogram,
// one global reserve atomic per (block,bucket), LDS-rank scatter.
__global__ void __launch_bounds__(256) k_cg1(const float* __restrict__ x0,
        const float* __restrict__ x1, const float* __restrict__ W1,
        __half* __restrict__ h0, __half* __restrict__ h1,
        const int* __restrict__ src0, const int* __restrict__ src1,
        const int* __restrict__ dst0, const int* __restrict__ dst1,
        const float* __restrict__ ew0, const float* __restrict__ ew1,
        uint2* __restrict__ stage, int* __restrict__ gcnt,
        int N, int E, int BPT, int GB, int B1, int TW2){
    __shared__ float As[2 * 8 * 256];      // 16 KB
    if ((int)blockIdx.x < GB){
        int t  = (int)blockIdx.x / BPT;
        int rb = ((int)blockIdx.x - t * BPT) * 256;
        gemm_tile<64,128,256,8,false,__half>(t ? x1 : x0, W1, t ? h1 : h0,
                                             nullptr, rb, N, As);
        return;
    }
    int t, blk;
    xcd_map((int)blockIdx.x - GB, TW2, NPB, t, blk);
    const int* src = t ? src1 : src0;
    const int* dst = t ? dst1 : dst0;
    const float* ew = t ? ew1 : ew0;
    uint2* stg = stage + (size_t)t * B1 * CAPB;
    int* gc = gcnt + t * B1;
    int* hist = (int*)As;                 // B1 ints (3.1KB) alias the GEMM As tile
    const int tid = threadIdx.x;
    for (int i = tid; i < B1; i += 256) hist[i] = 0;
    __syncthreads();
    int per = (E + NPB - 1) / NPB;
    int e0 = blk * per;
    int e1 = e0 + per; if (e1 > E) e1 = E;
    // pass 1: LDS histogram, 8-batched for ILP
    for (int e = e0 + tid; e < e1; e += 256 * EPT){
        int dl[EPT];
        #pragma unroll
        for (int q = 0; q < EPT; ++q){ int ee = e + q*256; dl[q] = (ee < e1) ? dst[ee] : -1; }
        #pragma unroll
        for (int q = 0; q < EPT; ++q) if (dl[q] >= 0) atomicAdd(&hist[dl[q] >> BSH], 1);
    }
    __syncthreads();
    // reserve: rotate start bucket per block to spread same-address contention
    int rot = (blk * 193) % B1;
    for (int i = tid; i < B1; i += 256){
        int b = i + rot; if (b >= B1) b -= B1;
        int h = hist[b];
        hist[b] = h ? atomicAdd(&gc[b], h) : 0;
    }
    __syncthreads();
    // pass 2: scatter packed records at LDS-atomic ranks, 8-batched
    for (int e = e0 + tid; e < e1; e += 256 * EPT){
        int dl[EPT], sl[EPT]; float wl[EPT];
        #pragma unroll
        for (int q = 0; q < EPT; ++q){
            int ee = e + q*256;
            if (ee < e1){ dl[q] = dst[ee]; sl[q] = src[ee]; wl[q] = fmaxf(ew[ee], 0.f); }
            else dl[q] = -1;
        }
        int r[EPT];
        #pragma unroll
        for (int q = 0; q < EPT; ++q)
            if (dl[q] >= 0) r[q] = atomicAdd(&hist[dl[q] >> BSH], 1);
        #pragma unroll
        for (int q = 0; q < EPT; ++q)
            if (dl[q] >= 0 && r[q] < CAPB)
                stg[(size_t)(dl[q] >> BSH) * CAPB + r[q]] =
                    make_uint2(__float_as_uint(wl[q]),
                               (unsigned)sl[q] | ((unsigned)(dl[q] & 63) << 16));
    }
}

// ===== pack: per-bucket 64-bin count+scan -> woff, sn (CSR, w as half2),
//       dinv, and fused dinv-prescale of this bucket's h1 rows =====
__global__ void __launch_bounds__(256) k_pack(const uint2* __restrict__ stage,
        const int* __restrict__ gcnt, int* __restrict__ woff,
        uint2* __restrict__ sn, float* __restrict__ dinv,
        __half* __restrict__ h1, int N, int E, int B1, int TW2){
    int t, b;
    xcd_map((int)blockIdx.x, TW2, B1, t, b);
    if (b >= B1) return;
    const int tid = threadIdx.x;
    const uint2* stg = stage + (size_t)t * B1 * CAPB;
    const int* gc = gcnt + t * B1;
    __shared__ int   wsum[4];
    __shared__ int   nh[64];
    __shared__ float nw[64];
    __shared__ int   offs[64];
    __shared__ float dvs[64];
    // exclusive bucket base = sum gc[0..b)
    int acc = 0;
    for (int i = tid; i < b; i += 256) acc += gc[i];
    #pragma unroll
    for (int o = 32; o; o >>= 1) acc += __shfl_down(acc, o);
    int lane = tid & 63, wv = tid >> 6;
    if (lane == 0) wsum[wv] = acc;
    if (tid < 64){ nh[tid] = 0; nw[tid] = 0.f; }
    __syncthreads();
    const int base = wsum[0] + wsum[1] + wsum[2] + wsum[3];
    int cnt = gc[b]; if (cnt > CAPB) cnt = CAPB;

    int   rr[7]; uint2 rec[7];
    #pragma unroll
    for (int q = 0; q < 7; ++q){
        int j = q * 256 + tid;
        if (j < cnt){
            uint2 v = stg[(size_t)b * CAPB + j];
            int nl = (v.y >> 16) & 63;
            rr[q] = atomicAdd(&nh[nl], 1);
            atomicAdd(&nw[nl], __uint_as_float(v.x));
            rec[q] = v;
        } else rec[q].y = 0xFFFFFFFFu;     // real records have bits 22..31 == 0
    }
    __syncthreads();
    if (tid < 64){
        int v = nh[tid], sc = v;
        #pragma unroll
        for (int o = 1; o < 64; o <<= 1){ int u = __shfl_up(sc, o); if (tid >= o) sc += u; }
        offs[tid] = sc - v;                // exclusive within-bucket prefix
        int n = (b << BSH) + tid;
        float dv = 0.f;
        if (n < N){
            dv = rsqrtf(FILLW + nw[tid]);
            woff[t * N + n] = base + sc - v;
            dinv[t * N + n] = dv;
        }
        dvs[tid] = dv;
    }
    __syncthreads();
    uint2* sno = sn + (size_t)t * E;
    #pragma unroll
    for (int q = 0; q < 7; ++q){
        if (rec[q].y != 0xFFFFFFFFu){
            int nl   = (int)((rec[q].y >> 16) & 63);
            unsigned srcv = rec[q].y & 0xFFFFu;
            __half hw = __float2half(__uint_as_float(rec[q].x));
            unsigned hu = (unsigned)__half_as_ushort(hw);
            sno[(size_t)base + offs[nl] + rr[q]] =
                make_uint2(srcv, hu | (hu << 16));
        }
    }
    // fused prescale: h1 rows of this bucket *= dinv (64 rows x 64 halves)
    __half2* hb = (__half2*)(h1 + ((size_t)t * N + ((size_t)b << BSH)) * 64);
    #pragma unroll
    for (int j = 0; j < 8; ++j){
        int idx = j * 256 + tid;
        int r = idx >> 5, cc = idx & 31;
        if ((b << BSH) + r < N){
            float2 f = __half22float2(hb[r * 32 + cc]);
            float dv = dvs[r];
            hb[r * 32 + cc] = __floats2half2_rn(f.x * dv, f.y * dv);
        }
    }
}

// ================== GEMM2: fp32 in, dinv-prescaled fp16 out ==================
// KC=8, no Ws: 8KB LDS, natural VGPR allocation -> 4 blocks/CU.
__global__ void __launch_bounds__(256) k_gemm2(const float* __restrict__ A0,
        const float* __restrict__ A1, const float* __restrict__ W,
        __half* __restrict__ C0, __half* __restrict__ C1,
        const float* __restrict__ dinv, int N, int BPT){
    __shared__ float As[2 * 8 * 128];      // 8 KB
    int t  = (int)blockIdx.x / BPT;
    int rb = ((int)blockIdx.x - t * BPT) * 128;
    gemm_tile<128,64,128,8,true,__half>(t ? A1 : A0, W, t ? C1 : C0,
                                        dinv + t * N, rb, N, As);
}

// ===== CSR gather-max, grouped-row geometry + packed-f16 math + XCD pinning =====
// UG sized so EG*UG ~= mean degree (16): F=64 -> UG=2 (16 slots), F=128 -> UG=4.
template<int F, int UG>
__global__ void __launch_bounds__(256) k_agg(const int* __restrict__ woff,
        const uint2* __restrict__ sn, const float* __restrict__ dinv,
        const __half* __restrict__ H0, const __half* __restrict__ H1,
        const float* __restrict__ bias, float* __restrict__ O0, float* __restrict__ O1,
        int N, int E, int BPT, int TW2){
    constexpr int LPR = F / 8;        // lanes per row
    constexpr int EG  = 64 / LPR;     // edges per group
    const int lane = threadIdx.x & 63, wv = threadIdx.x >> 6;
    int t, chunk;
    xcd_map((int)blockIdx.x, TW2, BPT, t, chunk);
    int n = chunk * 4 + wv;
    if (n >= N) return;
    int g = t * N + n;
    int beg = woff[g];
    int end = (n == N - 1) ? E : woff[g + 1];
    float di = dinv[g];
    int cnt = end - beg;
    const uint2* st = sn + (size_t)t * E;
    const __half* H = t ? H1 : H0;
    float* O = t ? O1 : O0;
    const int fl = lane % LPR;
    const int eg = lane / LPR;

    unsigned acc[4];
    {
        float4 hv = *(const float4*)(H + (size_t)n * F + fl * 8);
        const unsigned* hp = (const unsigned*)&hv;
        const unsigned two2 = 0x40004000u;       // half2(2.0, 2.0)
        #pragma unroll
        for (int k = 0; k < 4; ++k) acc[k] = pk_mul(hp[k], two2);
    }
    for (int base = 0; base < cnt; base += 64){
        int m = cnt - base; if (m > 64) m = 64;
        uint2 er = make_uint2(0u, 0u);
        if (lane < m) er = st[beg + base + lane];
        int es = (int)er.x;                            // src
        int ep = (int)er.y;                            // half2(w,w) bits
        for (int j = 0; j < m; j += EG * UG){
            int sl[UG], wl[UG]; float4 hv[UG];
            #pragma unroll
            for (int u = 0; u < UG; ++u){
                int jj = j + u * EG + eg; if (jj > m - 1) jj = m - 1;
                sl[u] = __shfl(es, jj);
                wl[u] = __shfl(ep, jj);
            }
            #pragma unroll
            for (int u = 0; u < UG; ++u)
                hv[u] = *(const float4*)(H + (size_t)sl[u] * F + fl * 8);
            #pragma unroll
            for (int u = 0; u < UG; ++u){
                const unsigned* hp = (const unsigned*)&hv[u];
                unsigned w2 = (unsigned)wl[u];
                #pragma unroll
                for (int k = 0; k < 4; ++k)
                    acc[k] = pk_max(acc[k], pk_mul(hp[k], w2));
            }
        }
    }
    #pragma unroll
    for (int msk = LPR; msk < 64; msk <<= 1)
        #pragma unroll
        for (int k = 0; k < 4; ++k){
            unsigned o = (unsigned)__shfl_xor((int)acc[k], msk);
            acc[k] = pk_max(acc[k], o);
        }
    if constexpr (F == 128){
        int f0 = fl * 8 + eg * 2;
        float2 f = __half22float2(*(__half2*)&acc[eg]);
        float2 bb = *(const float2*)(bias + f0);
        *(float2*)(O + (size_t)n * F + f0) =
            make_float2(di * f.x + bb.x, di * f.y + bb.y);
    } else {
        int f0 = fl * 8 + eg;
        unsigned av = acc[eg >> 1];
        unsigned short hs = (unsigned short)((eg & 1) ? (av >> 16) : (av & 0xFFFFu));
        float v = __half2float(__ushort_as_half(hs));
        O[(size_t)n * F + f0] = di * v + bias[f0];
    }
}

// ============================== host ==============================

extern "C" void kernel_launch(void* const* d_in, const int* in_sizes, int n_in,
                              void* d_out, int out_size, void* d_ws, size_t ws_size,
                              hipStream_t stream){
    const int E  = in_sizes[2];        // 800000
    const int F1 = in_sizes[7];        // 64
    const int F2 = in_sizes[9];        // 128
    const int IN = in_sizes[6] / F1;   // 128
    const int N  = in_sizes[0] / IN;   // 50000 (< 65536 for 8B staging records)
    const int B1 = (N + 63) >> BSH;    // 782 coarse buckets

    const float* W1 = (const float*)d_in[6];
    const float* b1 = (const float*)d_in[7];
    const float* W2 = (const float*)d_in[8];
    const float* b2 = (const float*)d_in[9];

    auto need = [&](int G){
        return (size_t)G * E * 8              // sn (uint2)
             + (size_t)G * N * F2 * 2         // hbuf (fp16)
             + (size_t)G * N * F1 * 4         // out1 (stage aliases: G*B1*CAPB*8 <= this)
             + (size_t)G * N * 8              // dinv + woff
             + (size_t)G * B1 * 4             // gcnt
             + 4096;
    };
    const int G = (ws_size >= need(2)) ? 2 : 1;
    const int TW2 = (G == 2);

    uint2*  sn    = (uint2*)d_ws;
    __half* hbuf  = (__half*)(sn + (size_t)G * E);
    float*  out1  = (float*)(hbuf + (size_t)G * N * F2);
    uint2*  stage = (uint2*)out1;              // G*B1*CAPB*8B = 22.4MB <= 25.6MB
    float*  dinv  = out1 + (size_t)G * N * F1;
    int*    woff  = (int*)(dinv + (size_t)G * N);
    int*    gcnt  = woff + (size_t)G * N;

    const int BPT1 = (N + 255) / 256;
    const int BPT2 = (N + 127) / 128;
    const int ABT  = (N + 3) / 4;
    const int GB   = G * BPT1;
    const int partGrid = TW2 ? (NPB / 4) * 8          : G * NPB;
    const int packGrid = TW2 ? ((B1 + 3) / 4) * 8     : G * B1;
    const int aggGrid  = TW2 ? ((ABT + 3) / 4) * 8    : G * ABT;

    for (int it = 0; it < 2; it += G){
        int t0 = it, t1 = (G == 2) ? it + 1 : it;
        const float* x0 = (const float*)d_in[t0*3], * x1 = (const float*)d_in[t1*3];
        const int* ei0 = (const int*)d_in[t0*3+1], * ei1 = (const int*)d_in[t1*3+1];
        const float* ew0 = (const float*)d_in[t0*3+2], * ew1 = (const float*)d_in[t1*3+2];
        const int* src0 = ei0, * dst0 = ei0 + E;
        const int* src1 = ei1, * dst1 = ei1 + E;
        __half* h1_0 = hbuf, * h1_1 = hbuf + (size_t)(G-1) * N * F1;
        __half* h2_0 = hbuf, * h2_1 = hbuf + (size_t)(G-1) * N * F2;
        float* o1_0 = out1, * o1_1 = out1 + (size_t)(G-1) * N * F1;
        float* go0 = (float*)d_out + (size_t)t0 * N * F2;
        float* go1 = (float*)d_out + (size_t)t1 * N * F2;

        hipMemsetAsync(gcnt, 0, (size_t)G * B1 * sizeof(int), stream);
        k_cg1<<<GB + partGrid, 256, 0, stream>>>(x0, x1, W1, h1_0, h1_1,
                                                 src0, src1, dst0, dst1, ew0, ew1,
                                                 stage, gcnt, N, E, BPT1, GB, B1, TW2);
        k_pack<<<packGrid, 256, 0, stream>>>(stage, gcnt, woff, sn, dinv, hbuf,
                                             N, E, B1, TW2);
        k_agg<64,2><<<aggGrid, 256, 0, stream>>>(woff, sn, dinv, h1_0, h1_1, b1,
                                                 o1_0, o1_1, N, E, ABT, TW2);
        k_gemm2<<<G * BPT2, 256, 0, stream>>>(o1_0, o1_1, W2, h2_0, h2_1, dinv, N, BPT2);
        k_agg<128,4><<<aggGrid, 256, 0, stream>>>(woff, sn, dinv, h2_0, h2_1, b2,
                                                  go0, go1, N, E, ABT, TW2);
    }
}

// Round 10
// 306.521 us; speedup vs baseline: 1.0034x; 1.0034x over previous
//
#include <hip/hip_runtime.h>
#include <hip/hip_fp16.h>

static constexpr float FILLW = 2.0f;
static constexpr int BSH  = 6;      // 64 nodes per coarse bucket
static constexpr int CAPB = 1792;   // bucket capacity (mean 1024, sd ~32 -> 24 sigma)
static constexpr int NPB  = 256;    // partition blocks per tower (per-block edges <= 4096)
static constexpr int KE   = 16;     // reg-cached edge slots per thread (per/256 <= 16)

// packed f16 helpers (VOP3P); keep values as 32-bit words
__device__ __forceinline__ unsigned pk_mul(unsigned a, unsigned b){
    unsigned r; asm("v_pk_mul_f16 %0, %1, %2" : "=v"(r) : "v"(a), "v"(b)); return r;
}
__device__ __forceinline__ unsigned pk_max(unsigned a, unsigned b){
    unsigned r; asm("v_pk_max_f16 %0, %1, %2" : "=v"(r) : "v"(a), "v"(b)); return r;
}

// ======================= register-blocked GEMM tile =======================
// Ws staging kept: measured faster than W-from-global (R9 regression: dropping
// Ws raised FETCH 37->80MB and slowed the GEMM inner loop).
template<int F, int K, int TR, int KC, bool SCALE, typename OutT>
__device__ __forceinline__ void gemm_tile(const float* __restrict__ A,
        const float* __restrict__ W, OutT* __restrict__ C,
        const float* __restrict__ dv, int rb, int N,
        float* __restrict__ Ws, float* __restrict__ As){
    constexpr int NCH = K / KC;
    constexpr int TRp = TR;           // PAD=0 verified conflict-free
    constexpr int CG  = F / 8;
    constexpr int LPT = TR * KC / 1024;
    const int tid = threadIdx.x;
    for (int i = tid; i < K * F / 4; i += 256)
        ((float4*)Ws)[i] = ((const float4*)W)[i];
    const int tx = tid % CG, ty = tid / CG;
    const int c0 = tx * 8, r0 = ty * 8;

    float acc[8][8];
    #pragma unroll
    for (int i = 0; i < 8; ++i)
        #pragma unroll
        for (int j = 0; j < 8; ++j) acc[i][j] = 0.f;

    float4 st[LPT];
    auto gload = [&](int kc){
        #pragma unroll
        for (int l2 = 0; l2 < LPT; ++l2){
            int l = l2 * 256 + tid;
            int r = l / (KC / 4);
            int kk = (l % (KC / 4)) * 4;
            int ar = rb + r; if (ar >= N) ar = N - 1;
            st[l2] = *(const float4*)(A + (size_t)ar * K + kc * KC + kk);
        }
    };
    auto swrite = [&](int buf){
        float* p = As + buf * (KC * TRp);
        #pragma unroll
        for (int l2 = 0; l2 < LPT; ++l2){
            int l = l2 * 256 + tid;
            int r = l / (KC / 4);
            int kk = (l % (KC / 4)) * 4;
            p[(kk+0)*TRp + r] = st[l2].x;
            p[(kk+1)*TRp + r] = st[l2].y;
            p[(kk+2)*TRp + r] = st[l2].z;
            p[(kk+3)*TRp + r] = st[l2].w;
        }
    };

    gload(0); swrite(0);
    __syncthreads();
    for (int kc = 0; kc < NCH; ++kc){
        if (kc + 1 < NCH) gload(kc + 1);
        const float* Ab = As + (kc & 1) * (KC * TRp);
        #pragma unroll
        for (int j = 0; j < KC; ++j){
            const float* wrow = Ws + (kc * KC + j) * F + c0;
            float4 w0 = *(const float4*)(wrow);
            float4 w1 = *(const float4*)(wrow + 4);
            float4 a0 = *(const float4*)(Ab + j * TRp + r0);
            float4 a1 = *(const float4*)(Ab + j * TRp + r0 + 4);
            float av[8] = {a0.x,a0.y,a0.z,a0.w,a1.x,a1.y,a1.z,a1.w};
            float wvv[8] = {w0.x,w0.y,w0.z,w0.w,w1.x,w1.y,w1.z,w1.w};
            #pragma unroll
            for (int rr = 0; rr < 8; ++rr)
                #pragma unroll
                for (int cc = 0; cc < 8; ++cc)
                    acc[rr][cc] = fmaf(av[rr], wvv[cc], acc[rr][cc]);
        }
        if (kc + 1 < NCH){ swrite((kc + 1) & 1); __syncthreads(); }
    }
    #pragma unroll
    for (int rr = 0; rr < 8; ++rr){
        int row = rb + r0 + rr;
        if (row < N){
            float scv = 1.0f;
            if constexpr (SCALE) scv = dv[row];
            if constexpr (sizeof(OutT) == 2){
                __half2 o2[4];
                #pragma unroll
                for (int q = 0; q < 4; ++q)
                    o2[q] = __floats2half2_rn(acc[rr][2*q]*scv, acc[rr][2*q+1]*scv);
                *(float4*)((__half*)C + (size_t)row * F + c0) = *(float4*)o2;
            } else {
                float4 o0 = {acc[rr][0]*scv, acc[rr][1]*scv, acc[rr][2]*scv, acc[rr][3]*scv};
                float4 o1 = {acc[rr][4]*scv, acc[rr][5]*scv, acc[rr][6]*scv, acc[rr][7]*scv};
                *(float4*)((float*)C + (size_t)row * F + c0)     = o0;
                *(float4*)((float*)C + (size_t)row * F + c0 + 4) = o1;
            }
        }
    }
}

// XCD-pinned decomposition: blockIdx%8 ~= XCD; XCDs 0-3 -> tower 0, 4-7 -> tower 1.
__device__ __forceinline__ void xcd_map(int c, int TW2, int LIN_BPT,
                                        int& t, int& chunk){
    if (TW2){ int x = c & 7; t = x >> 2; chunk = (c >> 3) * 4 + (x & 3); }
    else    { t = c / LIN_BPT; chunk = c - t * LIN_BPT; }
}

// ===== GEMM1 (fp16 out, both towers) =====
__global__ void __launch_bounds__(256) k_gemm1(const float* __restrict__ x0,
        const float* __restrict__ x1, const float* __restrict__ W1,
        __half* __restrict__ h0, __half* __restrict__ h1,
        int N, int BPT){
    __shared__ float Ws[64 * 128];
    __shared__ float As[2 * 8 * 256];
    int t  = (int)blockIdx.x / BPT;
    int rb = ((int)blockIdx.x - t * BPT) * 256;
    gemm_tile<64,128,256,8,false,__half>(t ? x1 : x0, W1, t ? h1 : h0,
                                         nullptr, rb, N, Ws, As);
}

// ===== partition (standalone, 4KB LDS): reg-cached edges across 3 phases =====
// Each thread loads its <=KE edges ONCE into registers (compile-time-indexed
// arrays), LDS-histograms, reserves per-(block,bucket) via one global atomic,
// then scatters at LDS ranks. Requires per-block edges <= KE*256.
__global__ void __launch_bounds__(256) k_part(const int* __restrict__ src0,
        const int* __restrict__ src1,
        const int* __restrict__ dst0, const int* __restrict__ dst1,
        const float* __restrict__ ew0, const float* __restrict__ ew1,
        uint2* __restrict__ stage, int* __restrict__ gcnt,
        int N, int E, int B1, int TW2){
    __shared__ int hist[1024];            // B1 <= 1024
    int t, blk;
    xcd_map((int)blockIdx.x, TW2, NPB, t, blk);
    const int* src = t ? src1 : src0;
    const int* dst = t ? dst1 : dst0;
    const float* ew = t ? ew1 : ew0;
    uint2* stg = stage + (size_t)t * B1 * CAPB;
    int* gc = gcnt + t * B1;
    const int tid = threadIdx.x;
    for (int i = tid; i < B1; i += 256) hist[i] = 0;
    __syncthreads();
    int per = (E + NPB - 1) / NPB;
    int e0 = blk * per;
    int e1 = e0 + per; if (e1 > E) e1 = E;
    int d[KE], s[KE]; float w[KE];
    #pragma unroll
    for (int k = 0; k < KE; ++k){
        int e = e0 + k * 256 + tid;
        if (e < e1){ d[k] = dst[e]; s[k] = src[e]; w[k] = fmaxf(ew[e], 0.f); }
        else d[k] = -1;
    }
    #pragma unroll
    for (int k = 0; k < KE; ++k)
        if (d[k] >= 0) atomicAdd(&hist[d[k] >> BSH], 1);
    __syncthreads();
    // reserve: rotate start bucket per block to spread same-address contention
    int rot = (blk * 193) % B1;
    for (int i = tid; i < B1; i += 256){
        int b = i + rot; if (b >= B1) b -= B1;
        int h = hist[b];
        hist[b] = h ? atomicAdd(&gc[b], h) : 0;
    }
    __syncthreads();
    int r[KE];
    #pragma unroll
    for (int k = 0; k < KE; ++k)
        if (d[k] >= 0) r[k] = atomicAdd(&hist[d[k] >> BSH], 1);
    #pragma unroll
    for (int k = 0; k < KE; ++k)
        if (d[k] >= 0 && r[k] < CAPB)
            stg[(size_t)(d[k] >> BSH) * CAPB + r[k]] =
                make_uint2(__float_as_uint(w[k]),
                           (unsigned)s[k] | ((unsigned)(d[k] & 63) << 16));
}

// ===== pack: per-bucket 64-bin count+scan -> woff, sn (CSR, w as half2),
//       dinv, and fused dinv-prescale of this bucket's h1 rows =====
__global__ void __launch_bounds__(256) k_pack(const uint2* __restrict__ stage,
        const int* __restrict__ gcnt, int* __restrict__ woff,
        uint2* __restrict__ sn, float* __restrict__ dinv,
        __half* __restrict__ h1, int N, int E, int B1, int TW2){
    int t, b;
    xcd_map((int)blockIdx.x, TW2, B1, t, b);
    if (b >= B1) return;
    const int tid = threadIdx.x;
    const uint2* stg = stage + (size_t)t * B1 * CAPB;
    const int* gc = gcnt + t * B1;
    __shared__ int   wsum[4];
    __shared__ int   nh[64];
    __shared__ float nw[64];
    __shared__ int   offs[64];
    __shared__ float dvs[64];
    // exclusive bucket base = sum gc[0..b)
    int acc = 0;
    for (int i = tid; i < b; i += 256) acc += gc[i];
    #pragma unroll
    for (int o = 32; o; o >>= 1) acc += __shfl_down(acc, o);
    int lane = tid & 63, wv = tid >> 6;
    if (lane == 0) wsum[wv] = acc;
    if (tid < 64){ nh[tid] = 0; nw[tid] = 0.f; }
    __syncthreads();
    const int base = wsum[0] + wsum[1] + wsum[2] + wsum[3];
    int cnt = gc[b]; if (cnt > CAPB) cnt = CAPB;

    int   rr[7]; uint2 rec[7];
    #pragma unroll
    for (int q = 0; q < 7; ++q){
        int j = q * 256 + tid;
        if (j < cnt){
            uint2 v = stg[(size_t)b * CAPB + j];
            int nl = (v.y >> 16) & 63;
            rr[q] = atomicAdd(&nh[nl], 1);
            atomicAdd(&nw[nl], __uint_as_float(v.x));
            rec[q] = v;
        } else rec[q].y = 0xFFFFFFFFu;     // real records have bits 22..31 == 0
    }
    __syncthreads();
    if (tid < 64){
        int v = nh[tid], sc = v;
        #pragma unroll
        for (int o = 1; o < 64; o <<= 1){ int u = __shfl_up(sc, o); if (tid >= o) sc += u; }
        offs[tid] = sc - v;                // exclusive within-bucket prefix
        int n = (b << BSH) + tid;
        float dv = 0.f;
        if (n < N){
            dv = rsqrtf(FILLW + nw[tid]);
            woff[t * N + n] = base + sc - v;
            dinv[t * N + n] = dv;
        }
        dvs[tid] = dv;
    }
    __syncthreads();
    uint2* sno = sn + (size_t)t * E;
    #pragma unroll
    for (int q = 0; q < 7; ++q){
        if (rec[q].y != 0xFFFFFFFFu){
            int nl   = (int)((rec[q].y >> 16) & 63);
            unsigned srcv = rec[q].y & 0xFFFFu;
            __half hw = __float2half(__uint_as_float(rec[q].x));
            unsigned hu = (unsigned)__half_as_ushort(hw);
            sno[(size_t)base + offs[nl] + rr[q]] =
                make_uint2(srcv, hu | (hu << 16));
        }
    }
    // fused prescale: h1 rows of this bucket *= dinv (64 rows x 64 halves)
    __half2* hb = (__half2*)(h1 + ((size_t)t * N + ((size_t)b << BSH)) * 64);
    #pragma unroll
    for (int j = 0; j < 8; ++j){
        int idx = j * 256 + tid;
        int r = idx >> 5, cc = idx & 31;
        if ((b << BSH) + r < N){
            float2 f = __half22float2(hb[r * 32 + cc]);
            float dv = dvs[r];
            hb[r * 32 + cc] = __floats2half2_rn(f.x * dv, f.y * dv);
        }
    }
}

// ================== GEMM2: fp32 in, dinv-prescaled fp16 out ==================
// KC=8, Ws staged: 40KB LDS, natural VGPR allocation.
__global__ void __launch_bounds__(256) k_gemm2(const float* __restrict__ A0,
        const float* __restrict__ A1, const float* __restrict__ W,
        __half* __restrict__ C0, __half* __restrict__ C1,
        const float* __restrict__ dinv, int N, int BPT){
    __shared__ float Ws[64 * 128];
    __shared__ float As[2 * 8 * 128];
    int t  = (int)blockIdx.x / BPT;
    int rb = ((int)blockIdx.x - t * BPT) * 128;
    gemm_tile<128,64,128,8,true,__half>(t ? A1 : A0, W, t ? C1 : C0,
                                        dinv + t * N, rb, N, Ws, As);
}

// ===== CSR gather-max, grouped-row geometry + packed-f16 math + XCD pinning =====
// UG sized so EG*UG ~= mean degree (16): F=64 -> UG=2 (16 slots), F=128 -> UG=4.
template<int F, int UG>
__global__ void __launch_bounds__(256) k_agg(const int* __restrict__ woff,
        const uint2* __restrict__ sn, const float* __restrict__ dinv,
        const __half* __restrict__ H0, const __half* __restrict__ H1,
        const float* __restrict__ bias, float* __restrict__ O0, float* __restrict__ O1,
        int N, int E, int BPT, int TW2){
    constexpr int LPR = F / 8;        // lanes per row
    constexpr int EG  = 64 / LPR;     // edges per group
    const int lane = threadIdx.x & 63, wv = threadIdx.x >> 6;
    int t, chunk;
    xcd_map((int)blockIdx.x, TW2, BPT, t, chunk);
    int n = chunk * 4 + wv;
    if (n >= N) return;
    int g = t * N + n;
    int beg = woff[g];
    int end = (n == N - 1) ? E : woff[g + 1];
    float di = dinv[g];
    int cnt = end - beg;
    const uint2* st = sn + (size_t)t * E;
    const __half* H = t ? H1 : H0;
    float* O = t ? O1 : O0;
    const int fl = lane % LPR;
    const int eg = lane / LPR;

    unsigned acc[4];
    {
        float4 hv = *(const float4*)(H + (size_t)n * F + fl * 8);
        const unsigned* hp = (const unsigned*)&hv;
        const unsigned two2 = 0x40004000u;       // half2(2.0, 2.0)
        #pragma unroll
        for (int k = 0; k < 4; ++k) acc[k] = pk_mul(hp[k], two2);
    }
    for (int base = 0; base < cnt; base += 64){
        int m = cnt - base; if (m > 64) m = 64;
        uint2 er = make_uint2(0u, 0u);
        if (lane < m) er = st[beg + base + lane];
        int es = (int)er.x;                            // src
        int ep = (int)er.y;                            // half2(w,w) bits
        for (int j = 0; j < m; j += EG * UG){
            int sl[UG], wl[UG]; float4 hv[UG];
            #pragma unroll
            for (int u = 0; u < UG; ++u){
                int jj = j + u * EG + eg; if (jj > m - 1) jj = m - 1;
                sl[u] = __shfl(es, jj);
                wl[u] = __shfl(ep, jj);
            }
            #pragma unroll
            for (int u = 0; u < UG; ++u)
                hv[u] = *(const float4*)(H + (size_t)sl[u] * F + fl * 8);
            #pragma unroll
            for (int u = 0; u < UG; ++u){
                const unsigned* hp = (const unsigned*)&hv[u];
                unsigned w2 = (unsigned)wl[u];
                #pragma unroll
                for (int k = 0; k < 4; ++k)
                    acc[k] = pk_max(acc[k], pk_mul(hp[k], w2));
            }
        }
    }
    #pragma unroll
    for (int msk = LPR; msk < 64; msk <<= 1)
        #pragma unroll
        for (int k = 0; k < 4; ++k){
            unsigned o = (unsigned)__shfl_xor((int)acc[k], msk);
            acc[k] = pk_max(acc[k], o);
        }
    if constexpr (F == 128){
        int f0 = fl * 8 + eg * 2;
        float2 f = __half22float2(*(__half2*)&acc[eg]);
        float2 bb = *(const float2*)(bias + f0);
        *(float2*)(O + (size_t)n * F + f0) =
            make_float2(di * f.x + bb.x, di * f.y + bb.y);
    } else {
        int f0 = fl * 8 + eg;
        unsigned av = acc[eg >> 1];
        unsigned short hs = (unsigned short)((eg & 1) ? (av >> 16) : (av & 0xFFFFu));
        float v = __half2float(__ushort_as_half(hs));
        O[(size_t)n * F + f0] = di * v + bias[f0];
    }
}

// ============================== host ==============================

extern "C" void kernel_launch(void* const* d_in, const int* in_sizes, int n_in,
                              void* d_out, int out_size, void* d_ws, size_t ws_size,
                              hipStream_t stream){
    const int E  = in_sizes[2];        // 800000 (must be <= NPB*KE*256)
    const int F1 = in_sizes[7];        // 64
    const int F2 = in_sizes[9];        // 128
    const int IN = in_sizes[6] / F1;   // 128
    const int N  = in_sizes[0] / IN;   // 50000 (< 65536 for 8B staging records)
    const int B1 = (N + 63) >> BSH;    // 782 coarse buckets

    const float* W1 = (const float*)d_in[6];
    const float* b1 = (const float*)d_in[7];
    const float* W2 = (const float*)d_in[8];
    const float* b2 = (const float*)d_in[9];

    auto need = [&](int G){
        return (size_t)G * E * 8              // sn (uint2)
             + (size_t)G * N * F2 * 2         // hbuf (fp16)
             + (size_t)G * N * F1 * 4         // out1 (stage aliases: G*B1*CAPB*8 <= this)
             + (size_t)G * N * 8              // dinv + woff
             + (size_t)G * B1 * 4             // gcnt
             + 4096;
    };
    const int G = (ws_size >= need(2)) ? 2 : 1;
    const int TW2 = (G == 2);

    uint2*  sn    = (uint2*)d_ws;
    __half* hbuf  = (__half*)(sn + (size_t)G * E);
    float*  out1  = (float*)(hbuf + (size_t)G * N * F2);
    uint2*  stage = (uint2*)out1;              // G*B1*CAPB*8B = 22.4MB <= 25.6MB
    float*  dinv  = out1 + (size_t)G * N * F1;
    int*    woff  = (int*)(dinv + (size_t)G * N);
    int*    gcnt  = woff + (size_t)G * N;

    const int BPT1 = (N + 255) / 256;
    const int BPT2 = (N + 127) / 128;
    const int ABT  = (N + 3) / 4;
    const int partGrid = TW2 ? (NPB / 4) * 8          : G * NPB;
    const int packGrid = TW2 ? ((B1 + 3) / 4) * 8     : G * B1;
    const int aggGrid  = TW2 ? ((ABT + 3) / 4) * 8    : G * ABT;

    for (int it = 0; it < 2; it += G){
        int t0 = it, t1 = (G == 2) ? it + 1 : it;
        const float* x0 = (const float*)d_in[t0*3], * x1 = (const float*)d_in[t1*3];
        const int* ei0 = (const int*)d_in[t0*3+1], * ei1 = (const int*)d_in[t1*3+1];
        const float* ew0 = (const float*)d_in[t0*3+2], * ew1 = (const float*)d_in[t1*3+2];
        const int* src0 = ei0, * dst0 = ei0 + E;
        const int* src1 = ei1, * dst1 = ei1 + E;
        __half* h1_0 = hbuf, * h1_1 = hbuf + (size_t)(G-1) * N * F1;
        __half* h2_0 = hbuf, * h2_1 = hbuf + (size_t)(G-1) * N * F2;
        float* o1_0 = out1, * o1_1 = out1 + (size_t)(G-1) * N * F1;
        float* go0 = (float*)d_out + (size_t)t0 * N * F2;
        float* go1 = (float*)d_out + (size_t)t1 * N * F2;

        hipMemsetAsync(gcnt, 0, (size_t)G * B1 * sizeof(int), stream);
        k_gemm1<<<G * BPT1, 256, 0, stream>>>(x0, x1, W1, h1_0, h1_1, N, BPT1);
        k_part<<<partGrid, 256, 0, stream>>>(src0, src1, dst0, dst1, ew0, ew1,
                                             stage, gcnt, N, E, B1, TW2);
        k_pack<<<packGrid, 256, 0, stream>>>(stage, gcnt, woff, sn, dinv, hbuf,
                                             N, E, B1, TW2);
        k_agg<64,2><<<aggGrid, 256, 0, stream>>>(woff, sn, dinv, h1_0, h1_1, b1,
                                                 o1_0, o1_1, N, E, ABT, TW2);
        k_gemm2<<<G * BPT2, 256, 0, stream>>>(o1_0, o1_1, W2, h2_0, h2_1, dinv, N, BPT2);
        k_agg<128,4><<<aggGrid, 256, 0, stream>>>(woff, sn, dinv, h2_0, h2_1, b2,
                                                  go0, go1, N, E, ABT, TW2);
    }
}

// Round 11
// 305.320 us; speedup vs baseline: 1.0074x; 1.0039x over previous
//
#include <hip/hip_runtime.h>
#include <hip/hip_fp16.h>

static constexpr float FILLW = 2.0f;
static constexpr int BSH  = 6;      // 64 nodes per coarse bucket
static constexpr int CAPB = 1792;   // bucket capacity (mean 1024, sd ~32 -> 24 sigma)
static constexpr int NPB  = 256;    // partition blocks per tower
static constexpr int EPT  = 8;      // partition edges/thread batch (ILP)

// packed f16 helpers (VOP3P); keep values as 32-bit words
__device__ __forceinline__ unsigned pk_mul(unsigned a, unsigned b){
    unsigned r; asm("v_pk_mul_f16 %0, %1, %2" : "=v"(r) : "v"(a), "v"(b)); return r;
}
__device__ __forceinline__ unsigned pk_max(unsigned a, unsigned b){
    unsigned r; asm("v_pk_max_f16 %0, %1, %2" : "=v"(r) : "v"(a), "v"(b)); return r;
}

// ======================= register-blocked GEMM tile =======================
// Ws staging kept: measured faster than W-from-global (R9: dropping Ws raised
// FETCH 37->80MB and slowed the GEMM inner loop).
template<int F, int K, int TR, int KC, bool SCALE, typename OutT>
__device__ __forceinline__ void gemm_tile(const float* __restrict__ A,
        const float* __restrict__ W, OutT* __restrict__ C,
        const float* __restrict__ dv, int rb, int N,
        float* __restrict__ Ws, float* __restrict__ As){
    constexpr int NCH = K / KC;
    constexpr int TRp = TR;           // PAD=0 verified conflict-free
    constexpr int CG  = F / 8;
    constexpr int LPT = TR * KC / 1024;
    const int tid = threadIdx.x;
    for (int i = tid; i < K * F / 4; i += 256)
        ((float4*)Ws)[i] = ((const float4*)W)[i];
    const int tx = tid % CG, ty = tid / CG;
    const int c0 = tx * 8, r0 = ty * 8;

    float acc[8][8];
    #pragma unroll
    for (int i = 0; i < 8; ++i)
        #pragma unroll
        for (int j = 0; j < 8; ++j) acc[i][j] = 0.f;

    float4 st[LPT];
    auto gload = [&](int kc){
        #pragma unroll
        for (int l2 = 0; l2 < LPT; ++l2){
            int l = l2 * 256 + tid;
            int r = l / (KC / 4);
            int kk = (l % (KC / 4)) * 4;
            int ar = rb + r; if (ar >= N) ar = N - 1;
            st[l2] = *(const float4*)(A + (size_t)ar * K + kc * KC + kk);
        }
    };
    auto swrite = [&](int buf){
        float* p = As + buf * (KC * TRp);
        #pragma unroll
        for (int l2 = 0; l2 < LPT; ++l2){
            int l = l2 * 256 + tid;
            int r = l / (KC / 4);
            int kk = (l % (KC / 4)) * 4;
            p[(kk+0)*TRp + r] = st[l2].x;
            p[(kk+1)*TRp + r] = st[l2].y;
            p[(kk+2)*TRp + r] = st[l2].z;
            p[(kk+3)*TRp + r] = st[l2].w;
        }
    };

    gload(0); swrite(0);
    __syncthreads();
    for (int kc = 0; kc < NCH; ++kc){
        if (kc + 1 < NCH) gload(kc + 1);
        const float* Ab = As + (kc & 1) * (KC * TRp);
        #pragma unroll
        for (int j = 0; j < KC; ++j){
            const float* wrow = Ws + (kc * KC + j) * F + c0;
            float4 w0 = *(const float4*)(wrow);
            float4 w1 = *(const float4*)(wrow + 4);
            float4 a0 = *(const float4*)(Ab + j * TRp + r0);
            float4 a1 = *(const float4*)(Ab + j * TRp + r0 + 4);
            float av[8] = {a0.x,a0.y,a0.z,a0.w,a1.x,a1.y,a1.z,a1.w};
            float wvv[8] = {w0.x,w0.y,w0.z,w0.w,w1.x,w1.y,w1.z,w1.w};
            #pragma unroll
            for (int rr = 0; rr < 8; ++rr)
                #pragma unroll
                for (int cc = 0; cc < 8; ++cc)
                    acc[rr][cc] = fmaf(av[rr], wvv[cc], acc[rr][cc]);
        }
        if (kc + 1 < NCH){ swrite((kc + 1) & 1); __syncthreads(); }
    }
    #pragma unroll
    for (int rr = 0; rr < 8; ++rr){
        int row = rb + r0 + rr;
        if (row < N){
            float scv = 1.0f;
            if constexpr (SCALE) scv = dv[row];
            if constexpr (sizeof(OutT) == 2){
                __half2 o2[4];
                #pragma unroll
                for (int q = 0; q < 4; ++q)
                    o2[q] = __floats2half2_rn(acc[rr][2*q]*scv, acc[rr][2*q+1]*scv);
                *(float4*)((__half*)C + (size_t)row * F + c0) = *(float4*)o2;
            } else {
                float4 o0 = {acc[rr][0]*scv, acc[rr][1]*scv, acc[rr][2]*scv, acc[rr][3]*scv};
                float4 o1 = {acc[rr][4]*scv, acc[rr][5]*scv, acc[rr][6]*scv, acc[rr][7]*scv};
                *(float4*)((float*)C + (size_t)row * F + c0)     = o0;
                *(float4*)((float*)C + (size_t)row * F + c0 + 4) = o1;
            }
        }
    }
}

// XCD-pinned decomposition: blockIdx%8 ~= XCD; XCDs 0-3 -> tower 0, 4-7 -> tower 1.
__device__ __forceinline__ void xcd_map(int c, int TW2, int LIN_BPT,
                                        int& t, int& chunk){
    if (TW2){ int x = c & 7; t = x >> 2; chunk = (c >> 3) * 4 + (x & 3); }
    else    { t = c / LIN_BPT; chunk = c - t * LIN_BPT; }
}

// ===== fused: GEMM1 (fp16 out, both towers) + coarse-bucket edge partition =====
__global__ void __launch_bounds__(256) k_cg1(const float* __restrict__ x0,
        const float* __restrict__ x1, const float* __restrict__ W1,
        __half* __restrict__ h0, __half* __restrict__ h1,
        const int* __restrict__ src0, const int* __restrict__ src1,
        const int* __restrict__ dst0, const int* __restrict__ dst1,
        const float* __restrict__ ew0, const float* __restrict__ ew1,
        uint2* __restrict__ stage, int* __restrict__ gcnt,
        int N, int E, int BPT, int GB, int B1, int TW2){
    __shared__ float Ws[64 * 128];
    __shared__ float As[2 * 8 * 256];
    if ((int)blockIdx.x < GB){
        int t  = (int)blockIdx.x / BPT;
        int rb = ((int)blockIdx.x - t * BPT) * 256;
        gemm_tile<64,128,256,8,false,__half>(t ? x1 : x0, W1, t ? h1 : h0,
                                             nullptr, rb, N, Ws, As);
        return;
    }
    int t, blk;
    xcd_map((int)blockIdx.x - GB, TW2, NPB, t, blk);
    const int* src = t ? src1 : src0;
    const int* dst = t ? dst1 : dst0;
    const float* ew = t ? ew1 : ew0;
    uint2* stg = stage + (size_t)t * B1 * CAPB;
    int* gc = gcnt + t * B1;
    int* hist = (int*)As;                 // B1 ints alias the GEMM As/Ws tile
    const int tid = threadIdx.x;
    for (int i = tid; i < B1; i += 256) hist[i] = 0;
    __syncthreads();
    int per = (E + NPB - 1) / NPB;
    int e0 = blk * per;
    int e1 = e0 + per; if (e1 > E) e1 = E;
    // pass 1: LDS histogram, 8-batched for ILP
    for (int e = e0 + tid; e < e1; e += 256 * EPT){
        int dl[EPT];
        #pragma unroll
        for (int q = 0; q < EPT; ++q){ int ee = e + q*256; dl[q] = (ee < e1) ? dst[ee] : -1; }
        #pragma unroll
        for (int q = 0; q < EPT; ++q) if (dl[q] >= 0) atomicAdd(&hist[dl[q] >> BSH], 1);
    }
    __syncthreads();
    // reserve: rotate start bucket per block to spread same-address contention
    int rot = (blk * 193) % B1;
    for (int i = tid; i < B1; i += 256){
        int b = i + rot; if (b >= B1) b -= B1;
        int h = hist[b];
        hist[b] = h ? atomicAdd(&gc[b], h) : 0;
    }
    __syncthreads();
    // pass 2: scatter packed records at LDS-atomic ranks, 8-batched
    for (int e = e0 + tid; e < e1; e += 256 * EPT){
        int dl[EPT], sl[EPT]; float wl[EPT];
        #pragma unroll
        for (int q = 0; q < EPT; ++q){
            int ee = e + q*256;
            if (ee < e1){ dl[q] = dst[ee]; sl[q] = src[ee]; wl[q] = fmaxf(ew[ee], 0.f); }
            else dl[q] = -1;
        }
        int r[EPT];
        #pragma unroll
        for (int q = 0; q < EPT; ++q)
            if (dl[q] >= 0) r[q] = atomicAdd(&hist[dl[q] >> BSH], 1);
        #pragma unroll
        for (int q = 0; q < EPT; ++q)
            if (dl[q] >= 0 && r[q] < CAPB)
                stg[(size_t)(dl[q] >> BSH) * CAPB + r[q]] =
                    make_uint2(__float_as_uint(wl[q]),
                               (unsigned)sl[q] | ((unsigned)(dl[q] & 63) << 16));
    }
}

// ===== pack: per-bucket 64-bin count+scan -> woff, sn (CSR, w as half2),
//       dinv, and fused dinv-prescale of this bucket's h1 rows =====
__global__ void __launch_bounds__(256) k_pack(const uint2* __restrict__ stage,
        const int* __restrict__ gcnt, int* __restrict__ woff,
        uint2* __restrict__ sn, float* __restrict__ dinv,
        __half* __restrict__ h1, int N, int E, int B1, int TW2){
    int t, b;
    xcd_map((int)blockIdx.x, TW2, B1, t, b);
    if (b >= B1) return;
    const int tid = threadIdx.x;
    const uint2* stg = stage + (size_t)t * B1 * CAPB;
    const int* gc = gcnt + t * B1;
    __shared__ int   wsum[4];
    __shared__ int   nh[64];
    __shared__ float nw[64];
    __shared__ int   offs[64];
    __shared__ float dvs[64];
    // exclusive bucket base = sum gc[0..b)
    int acc = 0;
    for (int i = tid; i < b; i += 256) acc += gc[i];
    #pragma unroll
    for (int o = 32; o; o >>= 1) acc += __shfl_down(acc, o);
    int lane = tid & 63, wv = tid >> 6;
    if (lane == 0) wsum[wv] = acc;
    if (tid < 64){ nh[tid] = 0; nw[tid] = 0.f; }
    __syncthreads();
    const int base = wsum[0] + wsum[1] + wsum[2] + wsum[3];
    int cnt = gc[b]; if (cnt > CAPB) cnt = CAPB;

    int   rr[7]; uint2 rec[7];
    #pragma unroll
    for (int q = 0; q < 7; ++q){
        int j = q * 256 + tid;
        if (j < cnt){
            uint2 v = stg[(size_t)b * CAPB + j];
            int nl = (v.y >> 16) & 63;
            rr[q] = atomicAdd(&nh[nl], 1);
            atomicAdd(&nw[nl], __uint_as_float(v.x));
            rec[q] = v;
        } else rec[q].y = 0xFFFFFFFFu;     // real records have bits 22..31 == 0
    }
    __syncthreads();
    if (tid < 64){
        int v = nh[tid], sc = v;
        #pragma unroll
        for (int o = 1; o < 64; o <<= 1){ int u = __shfl_up(sc, o); if (tid >= o) sc += u; }
        offs[tid] = sc - v;                // exclusive within-bucket prefix
        int n = (b << BSH) + tid;
        float dv = 0.f;
        if (n < N){
            dv = rsqrtf(FILLW + nw[tid]);
            woff[t * N + n] = base + sc - v;
            dinv[t * N + n] = dv;
        }
        dvs[tid] = dv;
    }
    __syncthreads();
    uint2* sno = sn + (size_t)t * E;
    #pragma unroll
    for (int q = 0; q < 7; ++q){
        if (rec[q].y != 0xFFFFFFFFu){
            int nl   = (int)((rec[q].y >> 16) & 63);
            unsigned srcv = rec[q].y & 0xFFFFu;
            __half hw = __float2half(__uint_as_float(rec[q].x));
            unsigned hu = (unsigned)__half_as_ushort(hw);
            sno[(size_t)base + offs[nl] + rr[q]] =
                make_uint2(srcv, hu | (hu << 16));
        }
    }
    // fused prescale: h1 rows of this bucket *= dinv (64 rows x 64 halves)
    __half2* hb = (__half2*)(h1 + ((size_t)t * N + ((size_t)b << BSH)) * 64);
    #pragma unroll
    for (int j = 0; j < 8; ++j){
        int idx = j * 256 + tid;
        int r = idx >> 5, cc = idx & 31;
        if ((b << BSH) + r < N){
            float2 f = __half22float2(hb[r * 32 + cc]);
            float dv = dvs[r];
            hb[r * 32 + cc] = __floats2half2_rn(f.x * dv, f.y * dv);
        }
    }
}

// ================== GEMM2: fp32 in, dinv-prescaled fp16 out ==================
__global__ void __launch_bounds__(256) k_gemm2(const float* __restrict__ A0,
        const float* __restrict__ A1, const float* __restrict__ W,
        __half* __restrict__ C0, __half* __restrict__ C1,
        const float* __restrict__ dinv, int N, int BPT){
    __shared__ float Ws[64 * 128];
    __shared__ float As[2 * 8 * 128];
    int t  = (int)blockIdx.x / BPT;
    int rb = ((int)blockIdx.x - t * BPT) * 128;
    gemm_tile<128,64,128,8,true,__half>(t ? A1 : A0, W, t ? C1 : C0,
                                        dinv + t * N, rb, N, Ws, As);
}

// ===== CSR gather-max: 2 nodes/wave, interleaved chains for doubled MLP =====
// Prior version compiled to VGPR=24 -> gathers serialized (latency-bound at
// 45% VALU / 49% HBM). Two independent per-wave chains force real in-flight
// gathers. Slot geometry per node unchanged (EG*UG = 16 = mean degree).
template<int F, int UG>
__global__ void __launch_bounds__(256) k_agg(const int* __restrict__ woff,
        const uint2* __restrict__ sn, const float* __restrict__ dinv,
        const __half* __restrict__ H0, const __half* __restrict__ H1,
        const float* __restrict__ bias, float* __restrict__ O0, float* __restrict__ O1,
        int N, int E, int BPT, int TW2){
    constexpr int LPR = F / 8;        // lanes per row
    constexpr int EG  = 64 / LPR;     // edges per group
    const int lane = threadIdx.x & 63, wv = threadIdx.x >> 6;
    int t, chunk;
    xcd_map((int)blockIdx.x, TW2, BPT, t, chunk);
    int n0 = chunk * 8 + wv * 2;      // 8 nodes/block, 2 per wave
    if (n0 >= N) return;
    const int n1 = n0 + 1;
    const bool has1 = (n1 < N);
    int g0 = t * N + n0;
    int beg0 = woff[g0];
    int end0 = (n0 == N - 1) ? E : woff[g0 + 1];
    int cnt0 = end0 - beg0;
    int beg1 = 0, cnt1 = 0;
    if (has1){
        beg1 = end0;                  // woff[g0+1] == end0 when n0 < N-1
        int end1 = (n1 == N - 1) ? E : woff[g0 + 2];
        cnt1 = end1 - beg1;
    }
    float di0 = dinv[g0];
    float di1 = has1 ? dinv[g0 + 1] : 0.f;
    const uint2* st = sn + (size_t)t * E;
    const __half* H = t ? H1 : H0;
    float* O = t ? O1 : O0;
    const int fl = lane % LPR;
    const int eg = lane / LPR;
    const unsigned two2 = 0x40004000u;       // half2(2.0, 2.0)

    unsigned a0[4], a1[4];
    {
        float4 hv = *(const float4*)(H + (size_t)n0 * F + fl * 8);
        const unsigned* hp = (const unsigned*)&hv;
        #pragma unroll
        for (int k = 0; k < 4; ++k) a0[k] = pk_mul(hp[k], two2);
    }
    if (has1){
        float4 hv = *(const float4*)(H + (size_t)n1 * F + fl * 8);
        const unsigned* hp = (const unsigned*)&hv;
        #pragma unroll
        for (int k = 0; k < 4; ++k) a1[k] = pk_mul(hp[k], two2);
    } else {
        #pragma unroll
        for (int k = 0; k < 4; ++k) a1[k] = 0u;
    }

    int mx = cnt0 > cnt1 ? cnt0 : cnt1;
    for (int base = 0; base < mx; base += 64){
        int m0 = cnt0 - base; if (m0 > 64) m0 = 64;
        int m1 = cnt1 - base; if (m1 > 64) m1 = 64;
        uint2 er0 = make_uint2(0u, 0u), er1 = make_uint2(0u, 0u);
        if (m0 > 0 && lane < m0) er0 = st[beg0 + base + lane];
        if (m1 > 0 && lane < m1) er1 = st[beg1 + base + lane];
        int es0 = (int)er0.x, ep0 = (int)er0.y;
        int es1 = (int)er1.x, ep1 = (int)er1.y;
        int mm = m0 > m1 ? m0 : m1;
        for (int j = 0; j < mm; j += EG * UG){
            bool p0 = (j < m0), p1 = (j < m1);     // wave-uniform
            int sl0[UG], wl0[UG], sl1[UG], wl1[UG];
            float4 hv0[UG], hv1[UG];
            if (p0){
                #pragma unroll
                for (int u = 0; u < UG; ++u){
                    int jj = j + u * EG + eg; if (jj > m0 - 1) jj = m0 - 1;
                    sl0[u] = __shfl(es0, jj); wl0[u] = __shfl(ep0, jj);
                }
                #pragma unroll
                for (int u = 0; u < UG; ++u)
                    hv0[u] = *(const float4*)(H + (size_t)sl0[u] * F + fl * 8);
            }
            if (p1){
                #pragma unroll
                for (int u = 0; u < UG; ++u){
                    int jj = j + u * EG + eg; if (jj > m1 - 1) jj = m1 - 1;
                    sl1[u] = __shfl(es1, jj); wl1[u] = __shfl(ep1, jj);
                }
                #pragma unroll
                for (int u = 0; u < UG; ++u)
                    hv1[u] = *(const float4*)(H + (size_t)sl1[u] * F + fl * 8);
            }
            if (p0){
                #pragma unroll
                for (int u = 0; u < UG; ++u){
                    const unsigned* hp = (const unsigned*)&hv0[u];
                    unsigned w2 = (unsigned)wl0[u];
                    #pragma unroll
                    for (int k = 0; k < 4; ++k)
                        a0[k] = pk_max(a0[k], pk_mul(hp[k], w2));
                }
            }
            if (p1){
                #pragma unroll
                for (int u = 0; u < UG; ++u){
                    const unsigned* hp = (const unsigned*)&hv1[u];
                    unsigned w2 = (unsigned)wl1[u];
                    #pragma unroll
                    for (int k = 0; k < 4; ++k)
                        a1[k] = pk_max(a1[k], pk_mul(hp[k], w2));
                }
            }
        }
    }
    #pragma unroll
    for (int msk = LPR; msk < 64; msk <<= 1)
        #pragma unroll
        for (int k = 0; k < 4; ++k){
            unsigned o0 = (unsigned)__shfl_xor((int)a0[k], msk);
            a0[k] = pk_max(a0[k], o0);
            unsigned o1 = (unsigned)__shfl_xor((int)a1[k], msk);
            a1[k] = pk_max(a1[k], o1);
        }
    if constexpr (F == 128){
        int f0 = fl * 8 + eg * 2;
        float2 bb = *(const float2*)(bias + f0);
        {
            float2 f = __half22float2(*(__half2*)&a0[eg]);
            *(float2*)(O + (size_t)n0 * F + f0) =
                make_float2(di0 * f.x + bb.x, di0 * f.y + bb.y);
        }
        if (has1){
            float2 f = __half22float2(*(__half2*)&a1[eg]);
            *(float2*)(O + (size_t)n1 * F + f0) =
                make_float2(di1 * f.x + bb.x, di1 * f.y + bb.y);
        }
    } else {
        int f0 = fl * 8 + eg;
        float bb = bias[f0];
        {
            unsigned av = a0[eg >> 1];
            unsigned short hs = (unsigned short)((eg & 1) ? (av >> 16) : (av & 0xFFFFu));
            O[(size_t)n0 * F + f0] = di0 * __half2float(__ushort_as_half(hs)) + bb;
        }
        if (has1){
            unsigned av = a1[eg >> 1];
            unsigned short hs = (unsigned short)((eg & 1) ? (av >> 16) : (av & 0xFFFFu));
            O[(size_t)n1 * F + f0] = di1 * __half2float(__ushort_as_half(hs)) + bb;
        }
    }
}

// ============================== host ==============================

extern "C" void kernel_launch(void* const* d_in, const int* in_sizes, int n_in,
                              void* d_out, int out_size, void* d_ws, size_t ws_size,
                              hipStream_t stream){
    const int E  = in_sizes[2];        // 800000
    const int F1 = in_sizes[7];        // 64
    const int F2 = in_sizes[9];        // 128
    const int IN = in_sizes[6] / F1;   // 128
    const int N  = in_sizes[0] / IN;   // 50000 (< 65536 for 8B staging records)
    const int B1 = (N + 63) >> BSH;    // 782 coarse buckets

    const float* W1 = (const float*)d_in[6];
    const float* b1 = (const float*)d_in[7];
    const float* W2 = (const float*)d_in[8];
    const float* b2 = (const float*)d_in[9];

    auto need = [&](int G){
        return (size_t)G * E * 8              // sn (uint2)
             + (size_t)G * N * F2 * 2         // hbuf (fp16)
             + (size_t)G * N * F1 * 4         // out1 (stage aliases: G*B1*CAPB*8 <= this)
             + (size_t)G * N * 8              // dinv + woff
             + (size_t)G * B1 * 4             // gcnt
             + 4096;
    };
    const int G = (ws_size >= need(2)) ? 2 : 1;
    const int TW2 = (G == 2);

    uint2*  sn    = (uint2*)d_ws;
    __half* hbuf  = (__half*)(sn + (size_t)G * E);
    float*  out1  = (float*)(hbuf + (size_t)G * N * F2);
    uint2*  stage = (uint2*)out1;              // G*B1*CAPB*8B = 22.4MB <= 25.6MB
    float*  dinv  = out1 + (size_t)G * N * F1;
    int*    woff  = (int*)(dinv + (size_t)G * N);
    int*    gcnt  = woff + (size_t)G * N;

    const int BPT1 = (N + 255) / 256;
    const int BPT2 = (N + 127) / 128;
    const int ABT  = (N + 7) / 8;              // 8 nodes/block (2 per wave)
    const int GB   = G * BPT1;
    const int partGrid = TW2 ? (NPB / 4) * 8          : G * NPB;
    const int packGrid = TW2 ? ((B1 + 3) / 4) * 8     : G * B1;
    const int aggGrid  = TW2 ? ((ABT + 3) / 4) * 8    : G * ABT;

    for (int it = 0; it < 2; it += G){
        int t0 = it, t1 = (G == 2) ? it + 1 : it;
        const float* x0 = (const float*)d_in[t0*3], * x1 = (const float*)d_in[t1*3];
        const int* ei0 = (const int*)d_in[t0*3+1], * ei1 = (const int*)d_in[t1*3+1];
        const float* ew0 = (const float*)d_in[t0*3+2], * ew1 = (const float*)d_in[t1*3+2];
        const int* src0 = ei0, * dst0 = ei0 + E;
        const int* src1 = ei1, * dst1 = ei1 + E;
        __half* h1_0 = hbuf, * h1_1 = hbuf + (size_t)(G-1) * N * F1;
        __half* h2_0 = hbuf, * h2_1 = hbuf + (size_t)(G-1) * N * F2;
        float* o1_0 = out1, * o1_1 = out1 + (size_t)(G-1) * N * F1;
        float* go0 = (float*)d_out + (size_t)t0 * N * F2;
        float* go1 = (float*)d_out + (size_t)t1 * N * F2;

        hipMemsetAsync(gcnt, 0, (size_t)G * B1 * sizeof(int), stream);
        k_cg1<<<GB + partGrid, 256, 0, stream>>>(x0, x1, W1, h1_0, h1_1,
                                                 src0, src1, dst0, dst1, ew0, ew1,
                                                 stage, gcnt, N, E, BPT1, GB, B1, TW2);
        k_pack<<<packGrid, 256, 0, stream>>>(stage, gcnt, woff, sn, dinv, hbuf,
                                             N, E, B1, TW2);
        k_agg<64,2><<<aggGrid, 256, 0, stream>>>(woff, sn, dinv, h1_0, h1_1, b1,
                                                 o1_0, o1_1, N, E, ABT, TW2);
        k_gemm2<<<G * BPT2, 256, 0, stream>>>(o1_0, o1_1, W2, h2_0, h2_1, dinv, N, BPT2);
        k_agg<128,4><<<aggGrid, 256, 0, stream>>>(woff, sn, dinv, h2_0, h2_1, b2,
                                                  go0, go1, N, E, ABT, TW2);
    }
}

// Round 12
// 301.101 us; speedup vs baseline: 1.0215x; 1.0140x over previous
//
#include <hip/hip_runtime.h>
#include <hip/hip_fp16.h>

static constexpr float FILLW = 2.0f;
static constexpr int BSH  = 6;      // 64 nodes per coarse bucket
static constexpr int CAPB = 1792;   // bucket capacity (mean 1024, sd ~32 -> 24 sigma)
static constexpr int NPB  = 256;    // partition blocks per tower
static constexpr int EPT  = 8;      // partition edges/thread batch (ILP)

// packed f16 helpers (VOP3P); keep values as 32-bit words
__device__ __forceinline__ unsigned pk_mul(unsigned a, unsigned b){
    unsigned r; asm("v_pk_mul_f16 %0, %1, %2" : "=v"(r) : "v"(a), "v"(b)); return r;
}
__device__ __forceinline__ unsigned pk_max(unsigned a, unsigned b){
    unsigned r; asm("v_pk_max_f16 %0, %1, %2" : "=v"(r) : "v"(a), "v"(b)); return r;
}

// ======================= register-blocked GEMM tile =======================
template<int F, int K, int TR, int KC, bool SCALE, typename OutT>
__device__ __forceinline__ void gemm_tile(const float* __restrict__ A,
        const float* __restrict__ W, OutT* __restrict__ C,
        const float* __restrict__ dv, int rb, int N,
        float* __restrict__ Ws, float* __restrict__ As){
    constexpr int NCH = K / KC;
    constexpr int TRp = TR;           // PAD=0 verified conflict-free for both uses
    constexpr int CG  = F / 8;
    constexpr int LPT = TR * KC / 1024;
    const int tid = threadIdx.x;
    for (int i = tid; i < K * F / 4; i += 256)
        ((float4*)Ws)[i] = ((const float4*)W)[i];
    const int tx = tid % CG, ty = tid / CG;
    const int c0 = tx * 8, r0 = ty * 8;

    float acc[8][8];
    #pragma unroll
    for (int i = 0; i < 8; ++i)
        #pragma unroll
        for (int j = 0; j < 8; ++j) acc[i][j] = 0.f;

    float4 st[LPT];
    auto gload = [&](int kc){
        #pragma unroll
        for (int l2 = 0; l2 < LPT; ++l2){
            int l = l2 * 256 + tid;
            int r = l / (KC / 4);
            int kk = (l % (KC / 4)) * 4;
            int ar = rb + r; if (ar >= N) ar = N - 1;
            st[l2] = *(const float4*)(A + (size_t)ar * K + kc * KC + kk);
        }
    };
    auto swrite = [&](int buf){
        float* p = As + buf * (KC * TRp);
        #pragma unroll
        for (int l2 = 0; l2 < LPT; ++l2){
            int l = l2 * 256 + tid;
            int r = l / (KC / 4);
            int kk = (l % (KC / 4)) * 4;
            p[(kk+0)*TRp + r] = st[l2].x;
            p[(kk+1)*TRp + r] = st[l2].y;
            p[(kk+2)*TRp + r] = st[l2].z;
            p[(kk+3)*TRp + r] = st[l2].w;
        }
    };

    gload(0); swrite(0);
    __syncthreads();
    for (int kc = 0; kc < NCH; ++kc){
        if (kc + 1 < NCH) gload(kc + 1);
        const float* Ab = As + (kc & 1) * (KC * TRp);
        #pragma unroll
        for (int j = 0; j < KC; ++j){
            const float* wrow = Ws + (kc * KC + j) * F + c0;
            float4 w0 = *(const float4*)(wrow);
            float4 w1 = *(const float4*)(wrow + 4);
            float4 a0 = *(const float4*)(Ab + j * TRp + r0);
            float4 a1 = *(const float4*)(Ab + j * TRp + r0 + 4);
            float av[8] = {a0.x,a0.y,a0.z,a0.w,a1.x,a1.y,a1.z,a1.w};
            float wvv[8] = {w0.x,w0.y,w0.z,w0.w,w1.x,w1.y,w1.z,w1.w};
            #pragma unroll
            for (int rr = 0; rr < 8; ++rr)
                #pragma unroll
                for (int cc = 0; cc < 8; ++cc)
                    acc[rr][cc] = fmaf(av[rr], wvv[cc], acc[rr][cc]);
        }
        if (kc + 1 < NCH){ swrite((kc + 1) & 1); __syncthreads(); }
    }
    #pragma unroll
    for (int rr = 0; rr < 8; ++rr){
        int row = rb + r0 + rr;
        if (row < N){
            float scv = 1.0f;
            if constexpr (SCALE) scv = dv[row];
            if constexpr (sizeof(OutT) == 2){
                __half2 o2[4];
                #pragma unroll
                for (int q = 0; q < 4; ++q)
                    o2[q] = __floats2half2_rn(acc[rr][2*q]*scv, acc[rr][2*q+1]*scv);
                *(float4*)((__half*)C + (size_t)row * F + c0) = *(float4*)o2;
            } else {
                float4 o0 = {acc[rr][0]*scv, acc[rr][1]*scv, acc[rr][2]*scv, acc[rr][3]*scv};
                float4 o1 = {acc[rr][4]*scv, acc[rr][5]*scv, acc[rr][6]*scv, acc[rr][7]*scv};
                *(float4*)((float*)C + (size_t)row * F + c0)     = o0;
                *(float4*)((float*)C + (size_t)row * F + c0 + 4) = o1;
            }
        }
    }
}

// XCD-pinned decomposition: blockIdx%8 ~= XCD; XCDs 0-3 -> tower 0, 4-7 -> tower 1.
__device__ __forceinline__ void xcd_map(int c, int TW2, int LIN_BPT,
                                        int& t, int& chunk){
    if (TW2){ int x = c & 7; t = x >> 2; chunk = (c >> 3) * 4 + (x & 3); }
    else    { t = c / LIN_BPT; chunk = c - t * LIN_BPT; }
}

// ===== fused: GEMM1 (fp16 out, both towers) + coarse-bucket edge partition =====
// Partition blocks: LDS histogram over B1 buckets, ONE global atomicAdd per
// (block,bucket) to reserve space, then scatter packed 8B records at LDS ranks.
// Measured faster than count/scan/scatter split (R7) and than standalone
// partition kernel (R10): fusion saves an edge re-read + launch.
__global__ void __launch_bounds__(256) k_cg1(const float* __restrict__ x0,
        const float* __restrict__ x1, const float* __restrict__ W1,
        __half* __restrict__ h0, __half* __restrict__ h1,
        const int* __restrict__ src0, const int* __restrict__ src1,
        const int* __restrict__ dst0, const int* __restrict__ dst1,
        const float* __restrict__ ew0, const float* __restrict__ ew1,
        uint2* __restrict__ stage, int* __restrict__ gcnt,
        int N, int E, int BPT, int GB, int B1, int TW2){
    __shared__ float Ws[64 * 128];
    __shared__ float As[2 * 8 * 256];
    if ((int)blockIdx.x < GB){
        int t  = (int)blockIdx.x / BPT;
        int rb = ((int)blockIdx.x - t * BPT) * 256;
        gemm_tile<64,128,256,8,false,__half>(t ? x1 : x0, W1, t ? h1 : h0,
                                             nullptr, rb, N, Ws, As);
        return;
    }
    int t, blk;
    xcd_map((int)blockIdx.x - GB, TW2, NPB, t, blk);
    const int* src = t ? src1 : src0;
    const int* dst = t ? dst1 : dst0;
    const float* ew = t ? ew1 : ew0;
    uint2* stg = stage + (size_t)t * B1 * CAPB;
    int* gc = gcnt + t * B1;
    int* hist = (int*)Ws;                 // B1 ints, aliases GEMM's W tile
    const int tid = threadIdx.x;
    for (int i = tid; i < B1; i += 256) hist[i] = 0;
    __syncthreads();
    int per = (E + NPB - 1) / NPB;
    int e0 = blk * per;
    int e1 = e0 + per; if (e1 > E) e1 = E;
    // pass 1: LDS histogram, 8-batched for ILP
    for (int e = e0 + tid; e < e1; e += 256 * EPT){
        int dl[EPT];
        #pragma unroll
        for (int q = 0; q < EPT; ++q){ int ee = e + q*256; dl[q] = (ee < e1) ? dst[ee] : -1; }
        #pragma unroll
        for (int q = 0; q < EPT; ++q) if (dl[q] >= 0) atomicAdd(&hist[dl[q] >> BSH], 1);
    }
    __syncthreads();
    // reserve: rotate start bucket per block to spread same-address contention
    int rot = (blk * 193) % B1;
    for (int i = tid; i < B1; i += 256){
        int b = i + rot; if (b >= B1) b -= B1;
        int h = hist[b];
        hist[b] = h ? atomicAdd(&gc[b], h) : 0;
    }
    __syncthreads();
    // pass 2: scatter packed records at LDS-atomic ranks, 8-batched
    for (int e = e0 + tid; e < e1; e += 256 * EPT){
        int dl[EPT], sl[EPT]; float wl[EPT];
        #pragma unroll
        for (int q = 0; q < EPT; ++q){
            int ee = e + q*256;
            if (ee < e1){ dl[q] = dst[ee]; sl[q] = src[ee]; wl[q] = fmaxf(ew[ee], 0.f); }
            else dl[q] = -1;
        }
        int r[EPT];
        #pragma unroll
        for (int q = 0; q < EPT; ++q)
            if (dl[q] >= 0) r[q] = atomicAdd(&hist[dl[q] >> BSH], 1);
        #pragma unroll
        for (int q = 0; q < EPT; ++q)
            if (dl[q] >= 0 && r[q] < CAPB)
                stg[(size_t)(dl[q] >> BSH) * CAPB + r[q]] =
                    make_uint2(__float_as_uint(wl[q]),
                               (unsigned)sl[q] | ((unsigned)(dl[q] & 63) << 16));
    }
}

// ===== pack: per-bucket 64-bin count+scan -> woff, sn (CSR, w as half2),
//       dinv, and fused dinv-prescale of this bucket's h1 rows =====
__global__ void __launch_bounds__(256) k_pack(const uint2* __restrict__ stage,
        const int* __restrict__ gcnt, int* __restrict__ woff,
        uint2* __restrict__ sn, float* __restrict__ dinv,
        __half* __restrict__ h1, int N, int E, int B1, int TW2){
    int t, b;
    xcd_map((int)blockIdx.x, TW2, B1, t, b);
    if (b >= B1) return;
    const int tid = threadIdx.x;
    const uint2* stg = stage + (size_t)t * B1 * CAPB;
    const int* gc = gcnt + t * B1;
    __shared__ int   wsum[4];
    __shared__ int   nh[64];
    __shared__ float nw[64];
    __shared__ int   offs[64];
    __shared__ float dvs[64];
    // exclusive bucket base = sum gc[0..b)
    int acc = 0;
    for (int i = tid; i < b; i += 256) acc += gc[i];
    #pragma unroll
    for (int o = 32; o; o >>= 1) acc += __shfl_down(acc, o);
    int lane = tid & 63, wv = tid >> 6;
    if (lane == 0) wsum[wv] = acc;
    if (tid < 64){ nh[tid] = 0; nw[tid] = 0.f; }
    __syncthreads();
    const int base = wsum[0] + wsum[1] + wsum[2] + wsum[3];
    int cnt = gc[b]; if (cnt > CAPB) cnt = CAPB;

    int   rr[7]; uint2 rec[7];
    #pragma unroll
    for (int q = 0; q < 7; ++q){
        int j = q * 256 + tid;
        if (j < cnt){
            uint2 v = stg[(size_t)b * CAPB + j];
            int nl = (v.y >> 16) & 63;
            rr[q] = atomicAdd(&nh[nl], 1);
            atomicAdd(&nw[nl], __uint_as_float(v.x));
            rec[q] = v;
        } else rec[q].y = 0xFFFFFFFFu;     // real records have bits 22..31 == 0
    }
    __syncthreads();
    if (tid < 64){
        int v = nh[tid], sc = v;
        #pragma unroll
        for (int o = 1; o < 64; o <<= 1){ int u = __shfl_up(sc, o); if (tid >= o) sc += u; }
        offs[tid] = sc - v;                // exclusive within-bucket prefix
        int n = (b << BSH) + tid;
        float dv = 0.f;
        if (n < N){
            dv = rsqrtf(FILLW + nw[tid]);
            woff[t * N + n] = base + sc - v;
            dinv[t * N + n] = dv;
        }
        dvs[tid] = dv;
    }
    __syncthreads();
    uint2* sno = sn + (size_t)t * E;
    #pragma unroll
    for (int q = 0; q < 7; ++q){
        if (rec[q].y != 0xFFFFFFFFu){
            int nl   = (int)((rec[q].y >> 16) & 63);
            unsigned srcv = rec[q].y & 0xFFFFu;
            __half hw = __float2half(__uint_as_float(rec[q].x));
            unsigned hu = (unsigned)__half_as_ushort(hw);
            sno[(size_t)base + offs[nl] + rr[q]] =
                make_uint2(srcv, hu | (hu << 16));
        }
    }
    // fused prescale: h1 rows of this bucket *= dinv (64 rows x 64 halves)
    __half2* hb = (__half2*)(h1 + ((size_t)t * N + ((size_t)b << BSH)) * 64);
    #pragma unroll
    for (int j = 0; j < 8; ++j){
        int idx = j * 256 + tid;
        int r = idx >> 5, cc = idx & 31;
        if ((b << BSH) + r < N){
            float2 f = __half22float2(hb[r * 32 + cc]);
            float dv = dvs[r];
            hb[r * 32 + cc] = __floats2half2_rn(f.x * dv, f.y * dv);
        }
    }
}

// ================== GEMM2: fp32 in, dinv-prescaled fp16 out ==================
// KC=8 (LPT=1, 40KB LDS), natural VGPR allocation -> 3-4 blocks/CU.
__global__ void __launch_bounds__(256) k_gemm2(const float* __restrict__ A0,
        const float* __restrict__ A1, const float* __restrict__ W,
        __half* __restrict__ C0, __half* __restrict__ C1,
        const float* __restrict__ dinv, int N, int BPT){
    __shared__ float Ws[64 * 128];
    __shared__ float As[2 * 8 * 128];
    int t  = (int)blockIdx.x / BPT;
    int rb = ((int)blockIdx.x - t * BPT) * 128;
    gemm_tile<128,64,128,8,true,__half>(t ? A1 : A0, W, t ? C1 : C0,
                                        dinv + t * N, rb, N, Ws, As);
}

// ===== CSR gather-max, grouped-row geometry + packed-f16 math + XCD pinning =====
// 1 node/wave (R11's 2-node/wave traded TLP for ILP at a net loss).
// UG sized so EG*UG ~= mean degree (16): F=64 -> UG=2, F=128 -> UG=4.
template<int F, int UG>
__global__ void __launch_bounds__(256) k_agg(const int* __restrict__ woff,
        const uint2* __restrict__ sn, const float* __restrict__ dinv,
        const __half* __restrict__ H0, const __half* __restrict__ H1,
        const float* __restrict__ bias, float* __restrict__ O0, float* __restrict__ O1,
        int N, int E, int BPT, int TW2){
    constexpr int LPR = F / 8;        // lanes per row
    constexpr int EG  = 64 / LPR;     // edges per group
    const int lane = threadIdx.x & 63, wv = threadIdx.x >> 6;
    int t, chunk;
    xcd_map((int)blockIdx.x, TW2, BPT, t, chunk);
    int n = chunk * 4 + wv;
    if (n >= N) return;
    int g = t * N + n;
    int beg = woff[g];
    int end = (n == N - 1) ? E : woff[g + 1];
    float di = dinv[g];
    int cnt = end - beg;
    const uint2* st = sn + (size_t)t * E;
    const __half* H = t ? H1 : H0;
    float* O = t ? O1 : O0;
    const int fl = lane % LPR;
    const int eg = lane / LPR;

    unsigned acc[4];
    {
        float4 hv = *(const float4*)(H + (size_t)n * F + fl * 8);
        const unsigned* hp = (const unsigned*)&hv;
        const unsigned two2 = 0x40004000u;       // half2(2.0, 2.0)
        #pragma unroll
        for (int k = 0; k < 4; ++k) acc[k] = pk_mul(hp[k], two2);
    }
    for (int base = 0; base < cnt; base += 64){
        int m = cnt - base; if (m > 64) m = 64;
        uint2 er = make_uint2(0u, 0u);
        if (lane < m) er = st[beg + base + lane];
        int es = (int)er.x;                            // src
        int ep = (int)er.y;                            // half2(w,w) bits
        for (int j = 0; j < m; j += EG * UG){
            int sl[UG], wl[UG]; float4 hv[UG];
            #pragma unroll
            for (int u = 0; u < UG; ++u){
                int jj = j + u * EG + eg; if (jj > m - 1) jj = m - 1;
                sl[u] = __shfl(es, jj);
                wl[u] = __shfl(ep, jj);
            }
            #pragma unroll
            for (int u = 0; u < UG; ++u)
                hv[u] = *(const float4*)(H + (size_t)sl[u] * F + fl * 8);
            #pragma unroll
            for (int u = 0; u < UG; ++u){
                const unsigned* hp = (const unsigned*)&hv[u];
                unsigned w2 = (unsigned)wl[u];
                #pragma unroll
                for (int k = 0; k < 4; ++k)
                    acc[k] = pk_max(acc[k], pk_mul(hp[k], w2));
            }
        }
    }
    #pragma unroll
    for (int msk = LPR; msk < 64; msk <<= 1)
        #pragma unroll
        for (int k = 0; k < 4; ++k){
            unsigned o = (unsigned)__shfl_xor((int)acc[k], msk);
            acc[k] = pk_max(acc[k], o);
        }
    if constexpr (F == 128){
        int f0 = fl * 8 + eg * 2;
        float2 f = __half22float2(*(__half2*)&acc[eg]);
        float2 bb = *(const float2*)(bias + f0);
        *(float2*)(O + (size_t)n * F + f0) =
            make_float2(di * f.x + bb.x, di * f.y + bb.y);
    } else {
        int f0 = fl * 8 + eg;
        unsigned av = acc[eg >> 1];
        unsigned short hs = (unsigned short)((eg & 1) ? (av >> 16) : (av & 0xFFFFu));
        float v = __half2float(__ushort_as_half(hs));
        O[(size_t)n * F + f0] = di * v + bias[f0];
    }
}

// ============================== host ==============================

extern "C" void kernel_launch(void* const* d_in, const int* in_sizes, int n_in,
                              void* d_out, int out_size, void* d_ws, size_t ws_size,
                              hipStream_t stream){
    const int E  = in_sizes[2];        // 800000
    const int F1 = in_sizes[7];        // 64
    const int F2 = in_sizes[9];        // 128
    const int IN = in_sizes[6] / F1;   // 128
    const int N  = in_sizes[0] / IN;   // 50000 (< 65536 for 8B staging records)
    const int B1 = (N + 63) >> BSH;    // 782 coarse buckets

    const float* W1 = (const float*)d_in[6];
    const float* b1 = (const float*)d_in[7];
    const float* W2 = (const float*)d_in[8];
    const float* b2 = (const float*)d_in[9];

    auto need = [&](int G){
        return (size_t)G * E * 8              // sn (uint2)
             + (size_t)G * N * F2 * 2         // hbuf (fp16)
             + (size_t)G * N * F1 * 4         // out1 (stage aliases: G*B1*CAPB*8 <= this)
             + (size_t)G * N * 8              // dinv + woff
             + (size_t)G * B1 * 4             // gcnt
             + 4096;
    };
    const int G = (ws_size >= need(2)) ? 2 : 1;
    const int TW2 = (G == 2);

    uint2*  sn    = (uint2*)d_ws;
    __half* hbuf  = (__half*)(sn + (size_t)G * E);
    float*  out1  = (float*)(hbuf + (size_t)G * N * F2);
    uint2*  stage = (uint2*)out1;              // G*B1*CAPB*8B = 22.4MB <= 25.6MB
    float*  dinv  = out1 + (size_t)G * N * F1;
    int*    woff  = (int*)(dinv + (size_t)G * N);
    int*    gcnt  = woff + (size_t)G * N;

    const int BPT1 = (N + 255) / 256;
    const int BPT2 = (N + 127) / 128;
    const int ABT  = (N + 3) / 4;
    const int GB   = G * BPT1;
    const int partGrid = TW2 ? (NPB / 4) * 8          : G * NPB;
    const int packGrid = TW2 ? ((B1 + 3) / 4) * 8     : G * B1;
    const int aggGrid  = TW2 ? ((ABT + 3) / 4) * 8    : G * ABT;

    for (int it = 0; it < 2; it += G){
        int t0 = it, t1 = (G == 2) ? it + 1 : it;
        const float* x0 = (const float*)d_in[t0*3], * x1 = (const float*)d_in[t1*3];
        const int* ei0 = (const int*)d_in[t0*3+1], * ei1 = (const int*)d_in[t1*3+1];
        const float* ew0 = (const float*)d_in[t0*3+2], * ew1 = (const float*)d_in[t1*3+2];
        const int* src0 = ei0, * dst0 = ei0 + E;
        const int* src1 = ei1, * dst1 = ei1 + E;
        __half* h1_0 = hbuf, * h1_1 = hbuf + (size_t)(G-1) * N * F1;
        __half* h2_0 = hbuf, * h2_1 = hbuf + (size_t)(G-1) * N * F2;
        float* o1_0 = out1, * o1_1 = out1 + (size_t)(G-1) * N * F1;
        float* go0 = (float*)d_out + (size_t)t0 * N * F2;
        float* go1 = (float*)d_out + (size_t)t1 * N * F2;

        hipMemsetAsync(gcnt, 0, (size_t)G * B1 * sizeof(int), stream);
        k_cg1<<<GB + partGrid, 256, 0, stream>>>(x0, x1, W1, h1_0, h1_1,
                                                 src0, src1, dst0, dst1, ew0, ew1,
                                                 stage, gcnt, N, E, BPT1, GB, B1, TW2);
        k_pack<<<packGrid, 256, 0, stream>>>(stage, gcnt, woff, sn, dinv, hbuf,
                                             N, E, B1, TW2);
        k_agg<64,2><<<aggGrid, 256, 0, stream>>>(woff, sn, dinv, h1_0, h1_1, b1,
                                                 o1_0, o1_1, N, E, ABT, TW2);
        k_gemm2<<<G * BPT2, 256, 0, stream>>>(o1_0, o1_1, W2, h2_0, h2_1, dinv, N, BPT2);
        k_agg<128,4><<<aggGrid, 256, 0, stream>>>(woff, sn, dinv, h2_0, h2_1, b2,
                                                  go0, go1, N, E, ABT, TW2);
    }
}